// Round 2
// baseline (853.605 us; speedup 1.0000x reference)
//
#include <hip/hip_runtime.h>
#include <hip/hip_bf16.h>
#include <stdint.h>

#define GCN_N 50000
#define GCN_E 800000
#define GCN_D 256

typedef __attribute__((ext_vector_type(8))) short bf16x8;
typedef __attribute__((ext_vector_type(4))) float f32x4;
typedef unsigned short ushort_t;

// ---------------- preprocessing kernels ----------------

__global__ void init_kernel(float* deg, int* counts, int* cursor, int n) {
    int i = blockIdx.x * blockDim.x + threadIdx.x;
    if (i < n) { deg[i] = 1.0f; counts[i] = 0; cursor[i] = 0; }
}

__global__ void edge_mlp_kernel(const float* __restrict__ attr,
                                const int* __restrict__ dst,
                                const float* __restrict__ mw1, const float* __restrict__ mb1,
                                const float* __restrict__ mw2, const float* __restrict__ mb2,
                                float* __restrict__ ew, float* __restrict__ deg,
                                int* __restrict__ counts, int e_count) {
    int e = blockIdx.x * blockDim.x + threadIdx.x;
    if (e >= e_count) return;
    float a = attr[e];
    float s = mb2[0];
#pragma unroll
    for (int j = 0; j < 8; ++j) {
        float hj = fmaf(a, mw1[j], mb1[j]);
        hj = fmaxf(hj, 0.0f);
        s = fmaf(hj, mw2[j], s);
    }
    float w = 1.0f / (1.0f + expf(-s));
    ew[e] = w;
    int d = dst[e];
    atomicAdd(&deg[d], w);
    atomicAdd(&counts[d], 1);
}

__global__ void node_kernel(const float* __restrict__ deg, float* __restrict__ dinv,
                            float* __restrict__ invdeg, int n) {
    int i = blockIdx.x * blockDim.x + threadIdx.x;
    if (i < n) {
        float d = deg[i];
        dinv[i] = rsqrtf(d);
        invdeg[i] = 1.0f / d;
    }
}

__global__ __launch_bounds__(1024) void scan1_kernel(const int* __restrict__ counts,
                                                     int* __restrict__ part,
                                                     int* __restrict__ bsum, int n) {
    __shared__ int s[1024];
    int tid = threadIdx.x;
    int i = blockIdx.x * 1024 + tid;
    int v = (i < n) ? counts[i] : 0;
    s[tid] = v;
    __syncthreads();
#pragma unroll
    for (int d = 1; d < 1024; d <<= 1) {
        int t = (tid >= d) ? s[tid - d] : 0;
        __syncthreads();
        s[tid] += t;
        __syncthreads();
    }
    if (i < n) part[i] = s[tid] - v;  // exclusive within block
    if (tid == 1023) bsum[blockIdx.x] = s[1023];
}

__global__ void scan2_kernel(int* bsum, int nb) {
    if (threadIdx.x == 0 && blockIdx.x == 0) {
        int run = 0;
        for (int b = 0; b < nb; ++b) { int t = bsum[b]; bsum[b] = run; run += t; }
    }
}

__global__ void scan3_kernel(const int* __restrict__ part, const int* __restrict__ bsum,
                             int* __restrict__ offs, int n, int e_total) {
    int i = blockIdx.x * blockDim.x + threadIdx.x;
    if (i < n) offs[i] = part[i] + bsum[i >> 10];
    if (i == 0) offs[n] = e_total;
}

__global__ void scatter_kernel(const int* __restrict__ src, const int* __restrict__ dst,
                               const float* __restrict__ ew, const float* __restrict__ dinv,
                               const int* __restrict__ offs, int* __restrict__ cursor,
                               int* __restrict__ csr_src, float* __restrict__ csr_w,
                               int e_count) {
    int e = blockIdx.x * blockDim.x + threadIdx.x;
    if (e >= e_count) return;
    int sN = src[e], dN = dst[e];
    int pos = offs[dN] + atomicAdd(&cursor[dN], 1);
    csr_src[pos] = sN;
    csr_w[pos] = dinv[sN] * ew[e] * dinv[dN];
}

// ---------------- W transpose + bf16 hi/lo split (256KB, once per layer) ----------------

__global__ void wconvert_kernel(const float* __restrict__ W,
                                ushort_t* __restrict__ wt_hi,
                                ushort_t* __restrict__ wt_lo) {
    int idx = blockIdx.x * 256 + threadIdx.x;   // 65536 elements
    int k = idx >> 8, n = idx & 255;            // coalesced read of W[k][n]
    float f = W[idx];
    unsigned u = __float_as_uint(f);
    ushort_t hi = (ushort_t)(u >> 16);          // truncation split: exact residual
    float r = f - __uint_as_float(u & 0xFFFF0000u);
    unsigned v = __float_as_uint(r);
    v += 0x7FFFu + ((v >> 16) & 1u);            // round-to-nearest-even
    ushort_t lo = (ushort_t)(v >> 16);
    wt_hi[n * 256 + k] = hi;                    // transposed: Wt[n][k]
    wt_lo[n * 256 + k] = lo;
}

// ---------------- MFMA GEMM: h = x @ W + b  (split-precision bf16) ----------------
// h ~= x_hi*W_hi + x_hi*W_lo + x_lo*W_hi ; rel err ~2^-16.
// Block 256 thr = 4 waves, each wave owns 32 rows x 256 cols (2 Mtiles x 16 Ntiles).
// A converted in-register from fp32 activations; B from L2-resident Wt[n][k] bf16.

__device__ __forceinline__ void split_f32x8(float4 f0, float4 f1, bf16x8& hi, bf16x8& lo) {
    float f[8] = {f0.x, f0.y, f0.z, f0.w, f1.x, f1.y, f1.z, f1.w};
#pragma unroll
    for (int i = 0; i < 8; ++i) {
        unsigned u = __float_as_uint(f[i]);
        hi[i] = (short)(u >> 16);
        float r = f[i] - __uint_as_float(u & 0xFFFF0000u);
        unsigned v = __float_as_uint(r);
        v += 0x7FFFu + ((v >> 16) & 1u);
        lo[i] = (short)(v >> 16);
    }
}

__global__ __launch_bounds__(256) void mfma_gemm_kernel(
        const float* __restrict__ x,          // [n_rows][256] fp32
        const ushort_t* __restrict__ wt_hi,   // [256][256] bf16 bits, [n][k]
        const ushort_t* __restrict__ wt_lo,
        const float* __restrict__ bias,
        float* __restrict__ out, int n_rows) {
    const int lane = threadIdx.x & 63;
    const int wv   = threadIdx.x >> 6;
    const int r16  = lane & 15;   // A row / B col / C col
    const int kg   = lane >> 4;   // k-group (0..3), 8 elems each
    const int row0 = blockIdx.x * 128 + wv * 32;

    f32x4 acc[2][16];
#pragma unroll
    for (int m = 0; m < 2; ++m)
#pragma unroll
        for (int nt = 0; nt < 16; ++nt)
            acc[m][nt] = (f32x4){0.f, 0.f, 0.f, 0.f};

#pragma unroll 2
    for (int kt = 0; kt < 8; ++kt) {
        bf16x8 a_hi[2], a_lo[2];
#pragma unroll
        for (int m = 0; m < 2; ++m) {
            int row = row0 + m * 16 + r16;
            float4 f0 = make_float4(0.f, 0.f, 0.f, 0.f), f1 = f0;
            if (row < n_rows) {
                const float* p = &x[row * GCN_D + kt * 32 + kg * 8];
                f0 = *(const float4*)p;
                f1 = *(const float4*)(p + 4);
            }
            split_f32x8(f0, f1, a_hi[m], a_lo[m]);
        }
#pragma unroll
        for (int nt = 0; nt < 16; ++nt) {
            int wo = (nt * 16 + r16) * GCN_D + kt * 32 + kg * 8;
            bf16x8 bh = *(const bf16x8*)&wt_hi[wo];
            bf16x8 bl = *(const bf16x8*)&wt_lo[wo];
#pragma unroll
            for (int m = 0; m < 2; ++m) {
                acc[m][nt] = __builtin_amdgcn_mfma_f32_16x16x32_bf16(a_hi[m], bh, acc[m][nt], 0, 0, 0);
                acc[m][nt] = __builtin_amdgcn_mfma_f32_16x16x32_bf16(a_lo[m], bh, acc[m][nt], 0, 0, 0);
                acc[m][nt] = __builtin_amdgcn_mfma_f32_16x16x32_bf16(a_hi[m], bl, acc[m][nt], 0, 0, 0);
            }
        }
    }

    // C/D layout: col = lane&15, row = (lane>>4)*4 + reg
#pragma unroll
    for (int nt = 0; nt < 16; ++nt) {
        float bv = bias[nt * 16 + r16];
#pragma unroll
        for (int m = 0; m < 2; ++m) {
#pragma unroll
            for (int r = 0; r < 4; ++r) {
                int row = row0 + m * 16 + kg * 4 + r;
                if (row < n_rows)
                    out[row * GCN_D + nt * 16 + r16] = acc[m][nt][r] + bv;
            }
        }
    }
}

// ---------------- SpMM: out = A_norm*h + diag(1/deg)*h, optional relu ----------------
// one wave per node; lane covers 4 contiguous cols (float4); edge loop unrolled x4
// so 4 row-gathers are in flight per wave (was 1 -> latency-bound at 47% fetch BW).

__global__ __launch_bounds__(256) void spmm_kernel(const float* __restrict__ h,
                                                   const int* __restrict__ offs,
                                                   const int* __restrict__ csr_src,
                                                   const float* __restrict__ csr_w,
                                                   const float* __restrict__ invdeg,
                                                   float* __restrict__ out, int n, int relu) {
    int wid = (blockIdx.x * blockDim.x + threadIdx.x) >> 6;
    int lane = threadIdx.x & 63;
    if (wid >= n) return;
    const float4* h4 = (const float4*)h;
    float4 acc = h4[wid * 64 + lane];
    float sw = invdeg[wid];
    acc.x *= sw; acc.y *= sw; acc.z *= sw; acc.w *= sw;
    int e0 = offs[wid], e1 = offs[wid + 1];
    int k = e0;
    for (; k + 4 <= e1; k += 4) {
        int s0 = csr_src[k], s1 = csr_src[k + 1], s2 = csr_src[k + 2], s3 = csr_src[k + 3];
        float w0 = csr_w[k], w1 = csr_w[k + 1], w2 = csr_w[k + 2], w3 = csr_w[k + 3];
        float4 v0 = h4[s0 * 64 + lane];
        float4 v1 = h4[s1 * 64 + lane];
        float4 v2 = h4[s2 * 64 + lane];
        float4 v3 = h4[s3 * 64 + lane];
        acc.x = fmaf(w0, v0.x, acc.x); acc.y = fmaf(w0, v0.y, acc.y);
        acc.z = fmaf(w0, v0.z, acc.z); acc.w = fmaf(w0, v0.w, acc.w);
        acc.x = fmaf(w1, v1.x, acc.x); acc.y = fmaf(w1, v1.y, acc.y);
        acc.z = fmaf(w1, v1.z, acc.z); acc.w = fmaf(w1, v1.w, acc.w);
        acc.x = fmaf(w2, v2.x, acc.x); acc.y = fmaf(w2, v2.y, acc.y);
        acc.z = fmaf(w2, v2.z, acc.z); acc.w = fmaf(w2, v2.w, acc.w);
        acc.x = fmaf(w3, v3.x, acc.x); acc.y = fmaf(w3, v3.y, acc.y);
        acc.z = fmaf(w3, v3.z, acc.z); acc.w = fmaf(w3, v3.w, acc.w);
    }
    for (; k < e1; ++k) {
        int s = csr_src[k];
        float w = csr_w[k];
        float4 hv = h4[s * 64 + lane];
        acc.x = fmaf(w, hv.x, acc.x);
        acc.y = fmaf(w, hv.y, acc.y);
        acc.z = fmaf(w, hv.z, acc.z);
        acc.w = fmaf(w, hv.w, acc.w);
    }
    if (relu) {
        acc.x = fmaxf(acc.x, 0.f);
        acc.y = fmaxf(acc.y, 0.f);
        acc.z = fmaxf(acc.z, 0.f);
        acc.w = fmaxf(acc.w, 0.f);
    }
    ((float4*)out)[wid * 64 + lane] = acc;
}

// ---------------- launch ----------------

extern "C" void kernel_launch(void* const* d_in, const int* in_sizes, int n_in,
                              void* d_out, int out_size, void* d_ws, size_t ws_size,
                              hipStream_t stream) {
    const float* x    = (const float*)d_in[0];
    const int*   ei   = (const int*)d_in[1];
    const float* attr = (const float*)d_in[2];
    const float* W1 = (const float*)d_in[3];  const float* b1 = (const float*)d_in[4];
    const float* W2 = (const float*)d_in[5];  const float* b2 = (const float*)d_in[6];
    const float* W3 = (const float*)d_in[7];  const float* b3 = (const float*)d_in[8];
    const float* mw1 = (const float*)d_in[9]; const float* mb1 = (const float*)d_in[10];
    const float* mw2 = (const float*)d_in[11];const float* mb2 = (const float*)d_in[12];
    float* out = (float*)d_out;

    const int N = GCN_N, E = GCN_E;
    const int* srcI = ei;
    const int* dstI = ei + E;

    float* ws = (float*)d_ws;
    float* ew     = ws;            // E
    float* deg    = ew + E;        // N
    float* dinv   = deg + N;       // N
    float* invdeg = dinv + N;      // N
    int* counts  = (int*)(invdeg + N);  // N
    int* cursor  = counts + N;          // N
    int* offs    = cursor + N;          // N+1
    int* bsum    = offs + N + 1;        // 64
    int* part    = bsum + 64;           // N
    int* csr_src = part + N;            // E
    float* csr_w = (float*)(csr_src + E);  // E
    float* h = (float*)(((uintptr_t)(csr_w + E) + 255) & ~(uintptr_t)255);  // N*256 f32
    ushort_t* wt = (ushort_t*)(((uintptr_t)(h + (size_t)N * GCN_D) + 255) & ~(uintptr_t)255);
    ushort_t* wt_hi1 = wt;            // 65536 each
    ushort_t* wt_lo1 = wt + 65536;
    ushort_t* wt_hi2 = wt + 2 * 65536;
    ushort_t* wt_lo2 = wt + 3 * 65536;
    ushort_t* wt_hi3 = wt + 4 * 65536;
    ushort_t* wt_lo3 = wt + 5 * 65536;

    init_kernel<<<(N + 255) / 256, 256, 0, stream>>>(deg, counts, cursor, N);
    edge_mlp_kernel<<<(E + 255) / 256, 256, 0, stream>>>(attr, dstI, mw1, mb1, mw2, mb2,
                                                         ew, deg, counts, E);
    node_kernel<<<(N + 255) / 256, 256, 0, stream>>>(deg, dinv, invdeg, N);
    int nb = (N + 1023) / 1024;
    scan1_kernel<<<nb, 1024, 0, stream>>>(counts, part, bsum, N);
    scan2_kernel<<<1, 64, 0, stream>>>(bsum, nb);
    scan3_kernel<<<(N + 255) / 256, 256, 0, stream>>>(part, bsum, offs, N, E);
    scatter_kernel<<<(E + 255) / 256, 256, 0, stream>>>(srcI, dstI, ew, dinv, offs, cursor,
                                                        csr_src, csr_w, E);
    wconvert_kernel<<<256, 256, 0, stream>>>(W1, wt_hi1, wt_lo1);
    wconvert_kernel<<<256, 256, 0, stream>>>(W2, wt_hi2, wt_lo2);
    wconvert_kernel<<<256, 256, 0, stream>>>(W3, wt_hi3, wt_lo3);

    const int gemm_grid = (N + 127) / 128;
    const int spmm_grid = (N * 64 + 255) / 256;

    // layer 1
    mfma_gemm_kernel<<<gemm_grid, 256, 0, stream>>>(x, wt_hi1, wt_lo1, b1, h, N);
    spmm_kernel<<<spmm_grid, 256, 0, stream>>>(h, offs, csr_src, csr_w, invdeg, out, N, 1);
    // layer 2
    mfma_gemm_kernel<<<gemm_grid, 256, 0, stream>>>(out, wt_hi2, wt_lo2, b2, h, N);
    spmm_kernel<<<spmm_grid, 256, 0, stream>>>(h, offs, csr_src, csr_w, invdeg, out, N, 1);
    // layer 3
    mfma_gemm_kernel<<<gemm_grid, 256, 0, stream>>>(out, wt_hi3, wt_lo3, b3, h, N);
    spmm_kernel<<<spmm_grid, 256, 0, stream>>>(h, offs, csr_src, csr_w, invdeg, out, N, 0);
}

// Round 3
// 502.690 us; speedup vs baseline: 1.6981x; 1.6981x over previous
//
#include <hip/hip_runtime.h>
#include <hip/hip_bf16.h>
#include <stdint.h>

#define GCN_N 50000
#define GCN_E 800000
#define GCN_D 256

typedef __attribute__((ext_vector_type(8))) short bf16x8;
typedef __attribute__((ext_vector_type(4))) float f32x4;
typedef unsigned short ushort_t;

__device__ __forceinline__ float bf2f(ushort_t u) {
    return __uint_as_float(((unsigned)u) << 16);
}
__device__ __forceinline__ ushort_t f2bf(float f) {
    unsigned v = __float_as_uint(f);
    v += 0x7FFFu + ((v >> 16) & 1u);   // round-to-nearest-even
    return (ushort_t)(v >> 16);
}

// ---------------- preprocessing kernels ----------------

__global__ void init_kernel(float* deg, int* counts, int* cursor, int n) {
    int i = blockIdx.x * blockDim.x + threadIdx.x;
    if (i < n) { deg[i] = 1.0f; counts[i] = 0; cursor[i] = 0; }
}

__global__ void edge_mlp_kernel(const float* __restrict__ attr,
                                const int* __restrict__ dst,
                                const float* __restrict__ mw1, const float* __restrict__ mb1,
                                const float* __restrict__ mw2, const float* __restrict__ mb2,
                                float* __restrict__ ew, float* __restrict__ deg,
                                int* __restrict__ counts, int e_count) {
    int e = blockIdx.x * blockDim.x + threadIdx.x;
    if (e >= e_count) return;
    float a = attr[e];
    float s = mb2[0];
#pragma unroll
    for (int j = 0; j < 8; ++j) {
        float hj = fmaf(a, mw1[j], mb1[j]);
        hj = fmaxf(hj, 0.0f);
        s = fmaf(hj, mw2[j], s);
    }
    float w = 1.0f / (1.0f + expf(-s));
    ew[e] = w;
    int d = dst[e];
    atomicAdd(&deg[d], w);
    atomicAdd(&counts[d], 1);
}

__global__ void node_kernel(const float* __restrict__ deg, float* __restrict__ dinv,
                            float* __restrict__ invdeg, int n) {
    int i = blockIdx.x * blockDim.x + threadIdx.x;
    if (i < n) {
        float d = deg[i];
        dinv[i] = rsqrtf(d);
        invdeg[i] = 1.0f / d;
    }
}

__global__ __launch_bounds__(1024) void scan1_kernel(const int* __restrict__ counts,
                                                     int* __restrict__ part,
                                                     int* __restrict__ bsum, int n) {
    __shared__ int s[1024];
    int tid = threadIdx.x;
    int i = blockIdx.x * 1024 + tid;
    int v = (i < n) ? counts[i] : 0;
    s[tid] = v;
    __syncthreads();
#pragma unroll
    for (int d = 1; d < 1024; d <<= 1) {
        int t = (tid >= d) ? s[tid - d] : 0;
        __syncthreads();
        s[tid] += t;
        __syncthreads();
    }
    if (i < n) part[i] = s[tid] - v;  // exclusive within block
    if (tid == 1023) bsum[blockIdx.x] = s[1023];
}

__global__ void scan2_kernel(int* bsum, int nb) {
    if (threadIdx.x == 0 && blockIdx.x == 0) {
        int run = 0;
        for (int b = 0; b < nb; ++b) { int t = bsum[b]; bsum[b] = run; run += t; }
    }
}

__global__ void scan3_kernel(const int* __restrict__ part, const int* __restrict__ bsum,
                             int* __restrict__ offs, int n, int e_total) {
    int i = blockIdx.x * blockDim.x + threadIdx.x;
    if (i < n) offs[i] = part[i] + bsum[i >> 10];
    if (i == 0) offs[n] = e_total;
}

__global__ void scatter_kernel(const int* __restrict__ src, const int* __restrict__ dst,
                               const float* __restrict__ ew, const float* __restrict__ dinv,
                               const int* __restrict__ offs, int* __restrict__ cursor,
                               int2* __restrict__ csr, int e_count) {
    int e = blockIdx.x * blockDim.x + threadIdx.x;
    if (e >= e_count) return;
    int sN = src[e], dN = dst[e];
    int pos = offs[dN] + atomicAdd(&cursor[dN], 1);
    float w = dinv[sN] * ew[e] * dinv[dN];
    csr[pos] = make_int2(sN, __float_as_int(w));
}

// ---------------- W -> bf16 hi/lo split in MFMA-fragment-major layout ----------------
// wtf[((kt*16 + nt)*64 + lane)*8 + j] = bf16(W[kt*32 + (lane>>4)*8 + j][nt*16 + (lane&15)])
// One block per kt (grid 8). Coalesced reads, LDS transpose, coalesced 16B writes.

__global__ __launch_bounds__(256) void wconvert_kernel(const float* __restrict__ W,
                                                       ushort_t* __restrict__ wtf_hi,
                                                       ushort_t* __restrict__ wtf_lo) {
    __shared__ ushort_t lds_hi[32][256];
    __shared__ ushort_t lds_lo[32][256];
    const int kt = blockIdx.x;
    const int tid = threadIdx.x;
    for (int c = 0; c < 32; ++c) {
        float f = W[(kt * 32 + c) * GCN_D + tid];
        unsigned u = __float_as_uint(f);
        ushort_t hi = (ushort_t)(u >> 16);               // truncation: exact residual
        float r = f - __uint_as_float(u & 0xFFFF0000u);
        lds_hi[c][tid] = hi;
        lds_lo[c][tid] = f2bf(r);
    }
    __syncthreads();
#pragma unroll
    for (int q = 0; q < 4; ++q) {
        int slot = q * 256 + tid;          // 0..1023 = nt*64 + lane
        int lane = slot & 63, nt = slot >> 6;
        int n = nt * 16 + (lane & 15);
        int kl = (lane >> 4) * 8;
        ushort_t h8[8], l8[8];
#pragma unroll
        for (int j = 0; j < 8; ++j) { h8[j] = lds_hi[kl + j][n]; l8[j] = lds_lo[kl + j][n]; }
        size_t o = ((size_t)(kt * 16 + nt) * 64 + lane) * 8;
#pragma unroll
        for (int j = 0; j < 8; ++j) { wtf_hi[o + j] = h8[j]; wtf_lo[o + j] = l8[j]; }
    }
}

// ---------------- MFMA GEMM: h_bf16 = bf16(x @ W + b)  (split-precision) ----------------
// Block 256 thr = 4 waves; wave owns 32 rows x 256 cols. B-loads are contiguous 1KB
// wave loads from fragment-major wtf. Epilogue transposes via per-wave LDS tile
// (stride 264 to spread banks) -> coalesced ushort4 row stores.

__device__ __forceinline__ void split_f32x8(float4 f0, float4 f1, bf16x8& hi, bf16x8& lo) {
    float f[8] = {f0.x, f0.y, f0.z, f0.w, f1.x, f1.y, f1.z, f1.w};
#pragma unroll
    for (int i = 0; i < 8; ++i) {
        unsigned u = __float_as_uint(f[i]);
        hi[i] = (short)(u >> 16);
        float r = f[i] - __uint_as_float(u & 0xFFFF0000u);
        lo[i] = (short)f2bf(r);
    }
}

__global__ __launch_bounds__(256) void mfma_gemm_kernel(
        const float* __restrict__ x,          // [n_rows][256] fp32
        const ushort_t* __restrict__ wtf_hi,  // fragment-major bf16 bits
        const ushort_t* __restrict__ wtf_lo,
        const float* __restrict__ bias,
        ushort_t* __restrict__ out_h,         // [n_rows][256] bf16
        int n_rows) {
    extern __shared__ ushort_t csmem[];       // 4 waves * 32 * 264
    const int lane = threadIdx.x & 63;
    const int wv   = threadIdx.x >> 6;
    const int r16  = lane & 15;
    const int kg   = lane >> 4;
    const int row0 = blockIdx.x * 128 + wv * 32;

    f32x4 acc[2][16];
#pragma unroll
    for (int m = 0; m < 2; ++m)
#pragma unroll
        for (int nt = 0; nt < 16; ++nt)
            acc[m][nt] = (f32x4){0.f, 0.f, 0.f, 0.f};

#pragma unroll 2
    for (int kt = 0; kt < 8; ++kt) {
        bf16x8 a_hi[2], a_lo[2];
#pragma unroll
        for (int m = 0; m < 2; ++m) {
            int row = row0 + m * 16 + r16;
            float4 f0 = make_float4(0.f, 0.f, 0.f, 0.f), f1 = f0;
            if (row < n_rows) {
                const float* p = &x[(size_t)row * GCN_D + kt * 32 + kg * 8];
                f0 = *(const float4*)p;
                f1 = *(const float4*)(p + 4);
            }
            split_f32x8(f0, f1, a_hi[m], a_lo[m]);
        }
        const bf16x8* bhp = (const bf16x8*)wtf_hi + (size_t)kt * 16 * 64 + lane;
        const bf16x8* blp = (const bf16x8*)wtf_lo + (size_t)kt * 16 * 64 + lane;
#pragma unroll
        for (int nt = 0; nt < 16; ++nt) {
            bf16x8 bh = bhp[nt * 64];
            bf16x8 bl = blp[nt * 64];
#pragma unroll
            for (int m = 0; m < 2; ++m) {
                acc[m][nt] = __builtin_amdgcn_mfma_f32_16x16x32_bf16(a_hi[m], bh, acc[m][nt], 0, 0, 0);
                acc[m][nt] = __builtin_amdgcn_mfma_f32_16x16x32_bf16(a_lo[m], bh, acc[m][nt], 0, 0, 0);
                acc[m][nt] = __builtin_amdgcn_mfma_f32_16x16x32_bf16(a_hi[m], bl, acc[m][nt], 0, 0, 0);
            }
        }
    }

    // C layout: col = lane&15, row = (lane>>4)*4 + reg  -> LDS tile -> coalesced stores
    ushort_t* my = csmem + wv * (32 * 264);
#pragma unroll
    for (int nt = 0; nt < 16; ++nt) {
        float bv = bias[nt * 16 + r16];
#pragma unroll
        for (int m = 0; m < 2; ++m)
#pragma unroll
            for (int r = 0; r < 4; ++r)
                my[(m * 16 + kg * 4 + r) * 264 + nt * 16 + r16] = f2bf(acc[m][nt][r] + bv);
    }
    __syncthreads();
#pragma unroll 4
    for (int r = 0; r < 32; ++r) {
        int row = row0 + r;
        if (row < n_rows) {
            ushort4 v = *(ushort4*)&my[r * 264 + lane * 4];
            *(ushort4*)&out_h[(size_t)row * GCN_D + lane * 4] = v;
        }
    }
}

// ---------------- SpMM: out = A_norm*h + diag(1/deg)*h, optional relu ----------------
// one wave per node; h gathered in bf16 (8B/lane), CSR packed int2, unroll x8.

__global__ __launch_bounds__(256) void spmm_kernel(const ushort_t* __restrict__ h,
                                                   const int* __restrict__ offs,
                                                   const int2* __restrict__ csr,
                                                   const float* __restrict__ invdeg,
                                                   float* __restrict__ out, int n, int relu) {
    int wid = (blockIdx.x * blockDim.x + threadIdx.x) >> 6;
    int lane = threadIdx.x & 63;
    if (wid >= n) return;
    const ushort4* h4 = (const ushort4*)h;
    ushort4 sv = h4[(size_t)wid * 64 + lane];
    float sw = invdeg[wid];
    float4 acc;
    acc.x = bf2f(sv.x) * sw; acc.y = bf2f(sv.y) * sw;
    acc.z = bf2f(sv.z) * sw; acc.w = bf2f(sv.w) * sw;
    int e0 = offs[wid], e1 = offs[wid + 1];
    int k = e0;
    for (; k + 8 <= e1; k += 8) {
        int2 ee[8]; ushort4 vv[8];
#pragma unroll
        for (int u = 0; u < 8; ++u) ee[u] = csr[k + u];
#pragma unroll
        for (int u = 0; u < 8; ++u) vv[u] = h4[(size_t)ee[u].x * 64 + lane];
#pragma unroll
        for (int u = 0; u < 8; ++u) {
            float w = __int_as_float(ee[u].y);
            acc.x = fmaf(w, bf2f(vv[u].x), acc.x);
            acc.y = fmaf(w, bf2f(vv[u].y), acc.y);
            acc.z = fmaf(w, bf2f(vv[u].z), acc.z);
            acc.w = fmaf(w, bf2f(vv[u].w), acc.w);
        }
    }
    for (; k < e1; ++k) {
        int2 e = csr[k];
        float w = __int_as_float(e.y);
        ushort4 hv = h4[(size_t)e.x * 64 + lane];
        acc.x = fmaf(w, bf2f(hv.x), acc.x);
        acc.y = fmaf(w, bf2f(hv.y), acc.y);
        acc.z = fmaf(w, bf2f(hv.z), acc.z);
        acc.w = fmaf(w, bf2f(hv.w), acc.w);
    }
    if (relu) {
        acc.x = fmaxf(acc.x, 0.f);
        acc.y = fmaxf(acc.y, 0.f);
        acc.z = fmaxf(acc.z, 0.f);
        acc.w = fmaxf(acc.w, 0.f);
    }
    ((float4*)out)[(size_t)wid * 64 + lane] = acc;
}

// ---------------- launch ----------------

extern "C" void kernel_launch(void* const* d_in, const int* in_sizes, int n_in,
                              void* d_out, int out_size, void* d_ws, size_t ws_size,
                              hipStream_t stream) {
    const float* x    = (const float*)d_in[0];
    const int*   ei   = (const int*)d_in[1];
    const float* attr = (const float*)d_in[2];
    const float* W1 = (const float*)d_in[3];  const float* b1 = (const float*)d_in[4];
    const float* W2 = (const float*)d_in[5];  const float* b2 = (const float*)d_in[6];
    const float* W3 = (const float*)d_in[7];  const float* b3 = (const float*)d_in[8];
    const float* mw1 = (const float*)d_in[9]; const float* mb1 = (const float*)d_in[10];
    const float* mw2 = (const float*)d_in[11];const float* mb2 = (const float*)d_in[12];
    float* out = (float*)d_out;

    const int N = GCN_N, E = GCN_E;
    const int* srcI = ei;
    const int* dstI = ei + E;

    float* ws = (float*)d_ws;
    float* ew     = ws;                 // E
    float* deg    = ew + E;             // N
    float* dinv   = deg + N;            // N
    float* invdeg = dinv + N;           // N
    int* counts  = (int*)(invdeg + N);  // N
    int* cursor  = counts + N;          // N
    int* offs    = cursor + N;          // N+1
    int* bsum    = offs + N + 1;        // 64
    int* part    = bsum + 64;           // N
    int2* csr    = (int2*)(((uintptr_t)(part + N) + 255) & ~(uintptr_t)255);      // E int2
    ushort_t* h  = (ushort_t*)(((uintptr_t)(csr + E) + 255) & ~(uintptr_t)255);   // N*256 bf16
    ushort_t* wtf = (ushort_t*)(((uintptr_t)(h + (size_t)N * GCN_D) + 255) & ~(uintptr_t)255);
    ushort_t* wtf_hi1 = wtf;            // 65536 each
    ushort_t* wtf_lo1 = wtf + 65536;
    ushort_t* wtf_hi2 = wtf + 2 * 65536;
    ushort_t* wtf_lo2 = wtf + 3 * 65536;
    ushort_t* wtf_hi3 = wtf + 4 * 65536;
    ushort_t* wtf_lo3 = wtf + 5 * 65536;

    init_kernel<<<(N + 255) / 256, 256, 0, stream>>>(deg, counts, cursor, N);
    edge_mlp_kernel<<<(E + 255) / 256, 256, 0, stream>>>(attr, dstI, mw1, mb1, mw2, mb2,
                                                         ew, deg, counts, E);
    node_kernel<<<(N + 255) / 256, 256, 0, stream>>>(deg, dinv, invdeg, N);
    int nb = (N + 1023) / 1024;
    scan1_kernel<<<nb, 1024, 0, stream>>>(counts, part, bsum, N);
    scan2_kernel<<<1, 64, 0, stream>>>(bsum, nb);
    scan3_kernel<<<(N + 255) / 256, 256, 0, stream>>>(part, bsum, offs, N, E);
    scatter_kernel<<<(E + 255) / 256, 256, 0, stream>>>(srcI, dstI, ew, dinv, offs, cursor,
                                                        csr, E);
    wconvert_kernel<<<8, 256, 0, stream>>>(W1, wtf_hi1, wtf_lo1);
    wconvert_kernel<<<8, 256, 0, stream>>>(W2, wtf_hi2, wtf_lo2);
    wconvert_kernel<<<8, 256, 0, stream>>>(W3, wtf_hi3, wtf_lo3);

    const int gemm_grid = (N + 127) / 128;
    const int spmm_grid = (N * 64 + 255) / 256;
    const size_t gemm_lds = 4 * 32 * 264 * sizeof(ushort_t);  // 67.6KB

    // layer 1
    mfma_gemm_kernel<<<gemm_grid, 256, gemm_lds, stream>>>(x, wtf_hi1, wtf_lo1, b1, h, N);
    spmm_kernel<<<spmm_grid, 256, 0, stream>>>(h, offs, csr, invdeg, out, N, 1);
    // layer 2
    mfma_gemm_kernel<<<gemm_grid, 256, gemm_lds, stream>>>(out, wtf_hi2, wtf_lo2, b2, h, N);
    spmm_kernel<<<spmm_grid, 256, 0, stream>>>(h, offs, csr, invdeg, out, N, 1);
    // layer 3
    mfma_gemm_kernel<<<gemm_grid, 256, gemm_lds, stream>>>(out, wtf_hi3, wtf_lo3, b3, h, N);
    spmm_kernel<<<spmm_grid, 256, 0, stream>>>(h, offs, csr, invdeg, out, N, 0);
}

// Round 4
// 422.536 us; speedup vs baseline: 2.0202x; 1.1897x over previous
//
#include <hip/hip_runtime.h>
#include <hip/hip_bf16.h>
#include <stdint.h>

#define GCN_N 50000
#define GCN_E 800000
#define GCN_D 256

typedef __attribute__((ext_vector_type(8))) short bf16x8;
typedef __attribute__((ext_vector_type(4))) float f32x4;
typedef unsigned short ushort_t;
typedef unsigned long long u64;

__device__ __forceinline__ float bf2f(ushort_t u) {
    return __uint_as_float(((unsigned)u) << 16);
}
__device__ __forceinline__ ushort_t f2bf(float f) {
    unsigned v = __float_as_uint(f);
    v += 0x7FFFu + ((v >> 16) & 1u);   // round-to-nearest-even
    return (ushort_t)(v >> 16);
}

// ---------------- preprocessing kernels ----------------

__global__ void init_kernel(u64* dc, int* cursor, int n) {
    int i = blockIdx.x * blockDim.x + threadIdx.x;
    if (i < n) { dc[i] = 0ull; cursor[i] = 0; }
}

// dc[d] packs: count in bits [40..], sum(w) as 2^-32 fixed point in bits [0..40)
__global__ void edge_mlp_kernel(const float* __restrict__ attr,
                                const int* __restrict__ dst,
                                const float* __restrict__ mw1, const float* __restrict__ mb1,
                                const float* __restrict__ mw2, const float* __restrict__ mb2,
                                float* __restrict__ ew, u64* __restrict__ dc, int e_count) {
    int e = blockIdx.x * blockDim.x + threadIdx.x;
    if (e >= e_count) return;
    float a = attr[e];
    float s = mb2[0];
#pragma unroll
    for (int j = 0; j < 8; ++j) {
        float hj = fmaf(a, mw1[j], mb1[j]);
        hj = fmaxf(hj, 0.0f);
        s = fmaf(hj, mw2[j], s);
    }
    float w = 1.0f / (1.0f + expf(-s));
    ew[e] = w;
    u64 pack = (1ull << 40) + (u64)((double)w * 4294967296.0);
    atomicAdd(&dc[dst[e]], pack);
}

__global__ void node_kernel(const u64* __restrict__ dc, float* __restrict__ dinv,
                            float* __restrict__ invdeg, int n) {
    int i = blockIdx.x * blockDim.x + threadIdx.x;
    if (i < n) {
        u64 v = dc[i];
        float wsum = (float)((double)(v & ((1ull << 40) - 1)) * (1.0 / 4294967296.0));
        float d = 1.0f + wsum;
        dinv[i] = rsqrtf(d);
        invdeg[i] = 1.0f / d;
    }
}

__global__ __launch_bounds__(1024) void scan1_kernel(const u64* __restrict__ dc,
                                                     int* __restrict__ part,
                                                     int* __restrict__ bsum, int n) {
    __shared__ int s[1024];
    int tid = threadIdx.x;
    int i = blockIdx.x * 1024 + tid;
    int v = (i < n) ? (int)(dc[i] >> 40) : 0;
    s[tid] = v;
    __syncthreads();
#pragma unroll
    for (int d = 1; d < 1024; d <<= 1) {
        int t = (tid >= d) ? s[tid - d] : 0;
        __syncthreads();
        s[tid] += t;
        __syncthreads();
    }
    if (i < n) part[i] = s[tid] - v;  // exclusive within block
    if (tid == 1023) bsum[blockIdx.x] = s[1023];
}

__global__ void scan2_kernel(int* bsum, int nb) {
    if (threadIdx.x == 0 && blockIdx.x == 0) {
        int run = 0;
        for (int b = 0; b < nb; ++b) { int t = bsum[b]; bsum[b] = run; run += t; }
    }
}

__global__ void scan3_kernel(const int* __restrict__ part, const int* __restrict__ bsum,
                             int* __restrict__ offs, int n, int e_total) {
    int i = blockIdx.x * blockDim.x + threadIdx.x;
    if (i < n) offs[i] = part[i] + bsum[i >> 10];
    if (i == 0) offs[n] = e_total;
}

__global__ void scatter_kernel(const int* __restrict__ src, const int* __restrict__ dst,
                               const float* __restrict__ ew, const float* __restrict__ dinv,
                               const int* __restrict__ offs, int* __restrict__ cursor,
                               int2* __restrict__ csr, int e_count) {
    int e = blockIdx.x * blockDim.x + threadIdx.x;
    if (e >= e_count) return;
    int sN = src[e], dN = dst[e];
    int pos = offs[dN] + atomicAdd(&cursor[dN], 1);
    float w = dinv[sN] * ew[e] * dinv[dN];
    csr[pos] = make_int2(sN, __float_as_int(w));
}

// ---------------- W -> bf16 hi/lo split in MFMA-fragment-major layout ----------------
// wtf[((kt*16 + nt)*64 + lane)*8 + j] = bf16(W[kt*32 + (lane>>4)*8 + j][nt*16 + (lane&15)])

__global__ __launch_bounds__(256) void wconvert_kernel(const float* __restrict__ W,
                                                       ushort_t* __restrict__ wtf_hi,
                                                       ushort_t* __restrict__ wtf_lo) {
    __shared__ ushort_t lds_hi[32][256];
    __shared__ ushort_t lds_lo[32][256];
    const int kt = blockIdx.x;
    const int tid = threadIdx.x;
    for (int c = 0; c < 32; ++c) {
        float f = W[(kt * 32 + c) * GCN_D + tid];
        unsigned u = __float_as_uint(f);
        ushort_t hi = (ushort_t)(u >> 16);               // truncation: exact residual
        float r = f - __uint_as_float(u & 0xFFFF0000u);
        lds_hi[c][tid] = hi;
        lds_lo[c][tid] = f2bf(r);
    }
    __syncthreads();
#pragma unroll
    for (int q = 0; q < 4; ++q) {
        int slot = q * 256 + tid;          // 0..1023 = nt*64 + lane
        int lane = slot & 63, nt = slot >> 6;
        int n = nt * 16 + (lane & 15);
        int kl = (lane >> 4) * 8;
        ushort_t h8[8], l8[8];
#pragma unroll
        for (int j = 0; j < 8; ++j) { h8[j] = lds_hi[kl + j][n]; l8[j] = lds_lo[kl + j][n]; }
        size_t o = ((size_t)(kt * 16 + nt) * 64 + lane) * 8;
#pragma unroll
        for (int j = 0; j < 8; ++j) { wtf_hi[o + j] = h8[j]; wtf_lo[o + j] = l8[j]; }
    }
}

// ---------------- MFMA GEMM (layer 1): fp32 x, split-precision ----------------

__device__ __forceinline__ void split_f32x8(float4 f0, float4 f1, bf16x8& hi, bf16x8& lo) {
    float f[8] = {f0.x, f0.y, f0.z, f0.w, f1.x, f1.y, f1.z, f1.w};
#pragma unroll
    for (int i = 0; i < 8; ++i) {
        unsigned u = __float_as_uint(f[i]);
        hi[i] = (short)(u >> 16);
        float r = f[i] - __uint_as_float(u & 0xFFFF0000u);
        lo[i] = (short)f2bf(r);
    }
}

__global__ __launch_bounds__(256) void mfma_gemm_f32_kernel(
        const float* __restrict__ x,          // [n_rows][256] fp32
        const ushort_t* __restrict__ wtf_hi,  // fragment-major bf16 bits
        const ushort_t* __restrict__ wtf_lo,
        const float* __restrict__ bias,
        ushort_t* __restrict__ out_h,         // [n_rows][256] bf16
        int n_rows) {
    extern __shared__ ushort_t csmem[];       // 4 waves * 32 * 264
    const int lane = threadIdx.x & 63;
    const int wv   = threadIdx.x >> 6;
    const int r16  = lane & 15;
    const int kg   = lane >> 4;
    const int row0 = blockIdx.x * 128 + wv * 32;

    f32x4 acc[2][16];
#pragma unroll
    for (int m = 0; m < 2; ++m)
#pragma unroll
        for (int nt = 0; nt < 16; ++nt)
            acc[m][nt] = (f32x4){0.f, 0.f, 0.f, 0.f};

#pragma unroll 2
    for (int kt = 0; kt < 8; ++kt) {
        bf16x8 a_hi[2], a_lo[2];
#pragma unroll
        for (int m = 0; m < 2; ++m) {
            int row = row0 + m * 16 + r16;
            float4 f0 = make_float4(0.f, 0.f, 0.f, 0.f), f1 = f0;
            if (row < n_rows) {
                const float* p = &x[(size_t)row * GCN_D + kt * 32 + kg * 8];
                f0 = *(const float4*)p;
                f1 = *(const float4*)(p + 4);
            }
            split_f32x8(f0, f1, a_hi[m], a_lo[m]);
        }
        const bf16x8* bhp = (const bf16x8*)wtf_hi + (size_t)kt * 16 * 64 + lane;
        const bf16x8* blp = (const bf16x8*)wtf_lo + (size_t)kt * 16 * 64 + lane;
#pragma unroll
        for (int nt = 0; nt < 16; ++nt) {
            bf16x8 bh = bhp[nt * 64];
            bf16x8 bl = blp[nt * 64];
#pragma unroll
            for (int m = 0; m < 2; ++m) {
                acc[m][nt] = __builtin_amdgcn_mfma_f32_16x16x32_bf16(a_hi[m], bh, acc[m][nt], 0, 0, 0);
                acc[m][nt] = __builtin_amdgcn_mfma_f32_16x16x32_bf16(a_lo[m], bh, acc[m][nt], 0, 0, 0);
                acc[m][nt] = __builtin_amdgcn_mfma_f32_16x16x32_bf16(a_hi[m], bl, acc[m][nt], 0, 0, 0);
            }
        }
    }

    ushort_t* my = csmem + wv * (32 * 264);
#pragma unroll
    for (int nt = 0; nt < 16; ++nt) {
        float bv = bias[nt * 16 + r16];
#pragma unroll
        for (int m = 0; m < 2; ++m)
#pragma unroll
            for (int r = 0; r < 4; ++r)
                my[(m * 16 + kg * 4 + r) * 264 + nt * 16 + r16] = f2bf(acc[m][nt][r] + bv);
    }
    __syncthreads();
#pragma unroll 4
    for (int r = 0; r < 32; ++r) {
        int row = row0 + r;
        if (row < n_rows) {
            ushort4 v = *(ushort4*)&my[r * 264 + lane * 4];
            *(ushort4*)&out_h[(size_t)row * GCN_D + lane * 4] = v;
        }
    }
}

// ---------------- MFMA GEMM (layers 2,3): bf16 A, W_hi only ----------------

__global__ __launch_bounds__(256) void mfma_gemm_bf16_kernel(
        const ushort_t* __restrict__ a_in,    // [n_rows][256] bf16
        const ushort_t* __restrict__ wtf_hi,
        const float* __restrict__ bias,
        ushort_t* __restrict__ out_h,         // [n_rows][256] bf16
        int n_rows) {
    extern __shared__ ushort_t csmem[];
    const int lane = threadIdx.x & 63;
    const int wv   = threadIdx.x >> 6;
    const int r16  = lane & 15;
    const int kg   = lane >> 4;
    const int row0 = blockIdx.x * 128 + wv * 32;

    f32x4 acc[2][16];
#pragma unroll
    for (int m = 0; m < 2; ++m)
#pragma unroll
        for (int nt = 0; nt < 16; ++nt)
            acc[m][nt] = (f32x4){0.f, 0.f, 0.f, 0.f};

#pragma unroll 2
    for (int kt = 0; kt < 8; ++kt) {
        bf16x8 a[2];
#pragma unroll
        for (int m = 0; m < 2; ++m) {
            int row = row0 + m * 16 + r16;
            bf16x8 av = (bf16x8){0, 0, 0, 0, 0, 0, 0, 0};
            if (row < n_rows)
                av = *(const bf16x8*)&a_in[(size_t)row * GCN_D + kt * 32 + kg * 8];
            a[m] = av;
        }
        const bf16x8* bhp = (const bf16x8*)wtf_hi + (size_t)kt * 16 * 64 + lane;
#pragma unroll
        for (int nt = 0; nt < 16; ++nt) {
            bf16x8 bh = bhp[nt * 64];
#pragma unroll
            for (int m = 0; m < 2; ++m)
                acc[m][nt] = __builtin_amdgcn_mfma_f32_16x16x32_bf16(a[m], bh, acc[m][nt], 0, 0, 0);
        }
    }

    ushort_t* my = csmem + wv * (32 * 264);
#pragma unroll
    for (int nt = 0; nt < 16; ++nt) {
        float bv = bias[nt * 16 + r16];
#pragma unroll
        for (int m = 0; m < 2; ++m)
#pragma unroll
            for (int r = 0; r < 4; ++r)
                my[(m * 16 + kg * 4 + r) * 264 + nt * 16 + r16] = f2bf(acc[m][nt][r] + bv);
    }
    __syncthreads();
#pragma unroll 4
    for (int r = 0; r < 32; ++r) {
        int row = row0 + r;
        if (row < n_rows) {
            ushort4 v = *(ushort4*)&my[r * 264 + lane * 4];
            *(ushort4*)&out_h[(size_t)row * GCN_D + lane * 4] = v;
        }
    }
}

// ---------------- SpMM: agg = A_norm*h + diag(1/deg)*h ----------------
// one wave per node; bf16 gathers (8B/lane), CSR packed int2, unroll x8.
// OUT_BF16: write bf16 + relu (layers 1,2). else fp32, no relu (layer 3).

template <int OUT_BF16>
__global__ __launch_bounds__(256) void spmm_kernel(const ushort_t* __restrict__ h,
                                                   const int* __restrict__ offs,
                                                   const int2* __restrict__ csr,
                                                   const float* __restrict__ invdeg,
                                                   void* __restrict__ outp, int n) {
    int wid = (blockIdx.x * blockDim.x + threadIdx.x) >> 6;
    int lane = threadIdx.x & 63;
    if (wid >= n) return;
    const ushort4* h4 = (const ushort4*)h;
    ushort4 sv = h4[(size_t)wid * 64 + lane];
    float sw = invdeg[wid];
    float4 acc;
    acc.x = bf2f(sv.x) * sw; acc.y = bf2f(sv.y) * sw;
    acc.z = bf2f(sv.z) * sw; acc.w = bf2f(sv.w) * sw;
    int e0 = offs[wid], e1 = offs[wid + 1];
    int k = e0;
    for (; k + 8 <= e1; k += 8) {
        int2 ee[8]; ushort4 vv[8];
#pragma unroll
        for (int u = 0; u < 8; ++u) ee[u] = csr[k + u];
#pragma unroll
        for (int u = 0; u < 8; ++u) vv[u] = h4[(size_t)ee[u].x * 64 + lane];
#pragma unroll
        for (int u = 0; u < 8; ++u) {
            float w = __int_as_float(ee[u].y);
            acc.x = fmaf(w, bf2f(vv[u].x), acc.x);
            acc.y = fmaf(w, bf2f(vv[u].y), acc.y);
            acc.z = fmaf(w, bf2f(vv[u].z), acc.z);
            acc.w = fmaf(w, bf2f(vv[u].w), acc.w);
        }
    }
    for (; k < e1; ++k) {
        int2 e = csr[k];
        float w = __int_as_float(e.y);
        ushort4 hv = h4[(size_t)e.x * 64 + lane];
        acc.x = fmaf(w, bf2f(hv.x), acc.x);
        acc.y = fmaf(w, bf2f(hv.y), acc.y);
        acc.z = fmaf(w, bf2f(hv.z), acc.z);
        acc.w = fmaf(w, bf2f(hv.w), acc.w);
    }
    if (OUT_BF16) {
        ushort4 o;
        o.x = f2bf(fmaxf(acc.x, 0.f));
        o.y = f2bf(fmaxf(acc.y, 0.f));
        o.z = f2bf(fmaxf(acc.z, 0.f));
        o.w = f2bf(fmaxf(acc.w, 0.f));
        ((ushort4*)outp)[(size_t)wid * 64 + lane] = o;
    } else {
        ((float4*)outp)[(size_t)wid * 64 + lane] = acc;
    }
}

// ---------------- launch ----------------

extern "C" void kernel_launch(void* const* d_in, const int* in_sizes, int n_in,
                              void* d_out, int out_size, void* d_ws, size_t ws_size,
                              hipStream_t stream) {
    const float* x    = (const float*)d_in[0];
    const int*   ei   = (const int*)d_in[1];
    const float* attr = (const float*)d_in[2];
    const float* W1 = (const float*)d_in[3];  const float* b1 = (const float*)d_in[4];
    const float* W2 = (const float*)d_in[5];  const float* b2 = (const float*)d_in[6];
    const float* W3 = (const float*)d_in[7];  const float* b3 = (const float*)d_in[8];
    const float* mw1 = (const float*)d_in[9]; const float* mb1 = (const float*)d_in[10];
    const float* mw2 = (const float*)d_in[11];const float* mb2 = (const float*)d_in[12];
    float* out = (float*)d_out;

    const int N = GCN_N, E = GCN_E;
    const int* srcI = ei;
    const int* dstI = ei + E;

    char* ws = (char*)d_ws;
    float* ew     = (float*)ws;                      ws += (size_t)E * 4;
    u64*   dc     = (u64*)(((uintptr_t)ws + 255) & ~(uintptr_t)255); ws = (char*)(dc + N);
    float* dinv   = (float*)ws;                      ws += (size_t)N * 4;
    float* invdeg = (float*)ws;                      ws += (size_t)N * 4;
    int*   cursor = (int*)ws;                        ws += (size_t)N * 4;
    int*   offs   = (int*)ws;                        ws += (size_t)(N + 1) * 4;
    int*   bsum   = (int*)ws;                        ws += 64 * 4;
    int*   part   = (int*)ws;                        ws += (size_t)N * 4;
    int2*  csr    = (int2*)(((uintptr_t)ws + 255) & ~(uintptr_t)255); ws = (char*)(csr + E);
    ushort_t* h   = (ushort_t*)(((uintptr_t)ws + 255) & ~(uintptr_t)255);  // N*256 bf16
    ws = (char*)(h + (size_t)N * GCN_D);
    ushort_t* act = (ushort_t*)(((uintptr_t)ws + 255) & ~(uintptr_t)255);  // N*256 bf16
    ws = (char*)(act + (size_t)N * GCN_D);
    ushort_t* wtf = (ushort_t*)(((uintptr_t)ws + 255) & ~(uintptr_t)255);
    ushort_t* wtf_hi1 = wtf;            // 65536 each
    ushort_t* wtf_lo1 = wtf + 65536;
    ushort_t* wtf_hi2 = wtf + 2 * 65536;
    ushort_t* wtf_lo2 = wtf + 3 * 65536;
    ushort_t* wtf_hi3 = wtf + 4 * 65536;
    ushort_t* wtf_lo3 = wtf + 5 * 65536;

    init_kernel<<<(N + 255) / 256, 256, 0, stream>>>(dc, cursor, N);
    edge_mlp_kernel<<<(E + 255) / 256, 256, 0, stream>>>(attr, dstI, mw1, mb1, mw2, mb2,
                                                         ew, dc, E);
    node_kernel<<<(N + 255) / 256, 256, 0, stream>>>(dc, dinv, invdeg, N);
    int nb = (N + 1023) / 1024;
    scan1_kernel<<<nb, 1024, 0, stream>>>(dc, part, bsum, N);
    scan2_kernel<<<1, 64, 0, stream>>>(bsum, nb);
    scan3_kernel<<<(N + 255) / 256, 256, 0, stream>>>(part, bsum, offs, N, E);
    scatter_kernel<<<(E + 255) / 256, 256, 0, stream>>>(srcI, dstI, ew, dinv, offs, cursor,
                                                        csr, E);
    wconvert_kernel<<<8, 256, 0, stream>>>(W1, wtf_hi1, wtf_lo1);
    wconvert_kernel<<<8, 256, 0, stream>>>(W2, wtf_hi2, wtf_lo2);
    wconvert_kernel<<<8, 256, 0, stream>>>(W3, wtf_hi3, wtf_lo3);

    const int gemm_grid = (N + 127) / 128;
    const int spmm_grid = (N * 64 + 255) / 256;
    const size_t gemm_lds = 4 * 32 * 264 * sizeof(ushort_t);  // 67.6KB

    // layer 1: x fp32 -> h ; spmm -> act (bf16, relu)
    mfma_gemm_f32_kernel<<<gemm_grid, 256, gemm_lds, stream>>>(x, wtf_hi1, wtf_lo1, b1, h, N);
    spmm_kernel<1><<<spmm_grid, 256, 0, stream>>>(h, offs, csr, invdeg, act, N);
    // layer 2: act bf16 -> h ; spmm -> act
    mfma_gemm_bf16_kernel<<<gemm_grid, 256, gemm_lds, stream>>>(act, wtf_hi2, b2, h, N);
    spmm_kernel<1><<<spmm_grid, 256, 0, stream>>>(h, offs, csr, invdeg, act, N);
    // layer 3: act bf16 -> h ; spmm -> d_out (fp32, no relu)
    mfma_gemm_bf16_kernel<<<gemm_grid, 256, gemm_lds, stream>>>(act, wtf_hi3, b3, h, N);
    spmm_kernel<0><<<spmm_grid, 256, 0, stream>>>(h, offs, csr, invdeg, out, N);
}

// Round 5
// 412.580 us; speedup vs baseline: 2.0689x; 1.0241x over previous
//
#include <hip/hip_runtime.h>
#include <hip/hip_bf16.h>
#include <stdint.h>

#define GCN_N 50000
#define GCN_E 800000
#define GCN_D 256

typedef __attribute__((ext_vector_type(8))) short bf16x8;
typedef __attribute__((ext_vector_type(4))) float f32x4;
typedef unsigned short ushort_t;
typedef unsigned long long u64;

__device__ __forceinline__ float bf2f(ushort_t u) {
    return __uint_as_float(((unsigned)u) << 16);
}
__device__ __forceinline__ ushort_t f2bf(float f) {
    unsigned v = __float_as_uint(f);
    v += 0x7FFFu + ((v >> 16) & 1u);   // round-to-nearest-even
    return (ushort_t)(v >> 16);
}

// ---------------- preprocessing kernels ----------------

__global__ void init_kernel(u64* dc, int* cursor, int n) {
    int i = blockIdx.x * blockDim.x + threadIdx.x;
    if (i < n) { dc[i] = 0ull; cursor[i] = 0; }
}

// dc[d] packs: count in bits [40..], sum(w) as 2^-32 fixed point in bits [0..40)
__global__ void edge_mlp_kernel(const float* __restrict__ attr,
                                const int* __restrict__ dst,
                                const float* __restrict__ mw1, const float* __restrict__ mb1,
                                const float* __restrict__ mw2, const float* __restrict__ mb2,
                                float* __restrict__ ew, u64* __restrict__ dc, int e_count) {
    int e = blockIdx.x * blockDim.x + threadIdx.x;
    if (e >= e_count) return;
    float a = attr[e];
    float s = mb2[0];
#pragma unroll
    for (int j = 0; j < 8; ++j) {
        float hj = fmaf(a, mw1[j], mb1[j]);
        hj = fmaxf(hj, 0.0f);
        s = fmaf(hj, mw2[j], s);
    }
    float w = 1.0f / (1.0f + expf(-s));
    ew[e] = w;
    u64 pack = (1ull << 40) + (u64)((double)w * 4294967296.0);
    atomicAdd(&dc[dst[e]], pack);
}

__global__ void node_kernel(const u64* __restrict__ dc, float* __restrict__ dinv,
                            float* __restrict__ invdeg, int n) {
    int i = blockIdx.x * blockDim.x + threadIdx.x;
    if (i < n) {
        u64 v = dc[i];
        float wsum = (float)((double)(v & ((1ull << 40) - 1)) * (1.0 / 4294967296.0));
        float d = 1.0f + wsum;
        dinv[i] = rsqrtf(d);
        invdeg[i] = 1.0f / d;
    }
}

__global__ __launch_bounds__(1024) void scan1_kernel(const u64* __restrict__ dc,
                                                     int* __restrict__ part,
                                                     int* __restrict__ bsum, int n) {
    __shared__ int s[1024];
    int tid = threadIdx.x;
    int i = blockIdx.x * 1024 + tid;
    int v = (i < n) ? (int)(dc[i] >> 40) : 0;
    s[tid] = v;
    __syncthreads();
#pragma unroll
    for (int d = 1; d < 1024; d <<= 1) {
        int t = (tid >= d) ? s[tid - d] : 0;
        __syncthreads();
        s[tid] += t;
        __syncthreads();
    }
    if (i < n) part[i] = s[tid] - v;  // exclusive within block
    if (tid == 1023) bsum[blockIdx.x] = s[1023];
}

// wave64 shuffle scan over block sums (nb <= 64)
__global__ void scan2_kernel(int* bsum, int nb) {
    int t = threadIdx.x;
    int orig = (t < nb) ? bsum[t] : 0;
    int v = orig;
#pragma unroll
    for (int d = 1; d < 64; d <<= 1) {
        int u = __shfl_up(v, d, 64);
        if (t >= d) v += u;
    }
    if (t < nb) bsum[t] = v - orig;   // exclusive
}

__global__ void scan3_kernel(const int* __restrict__ part, const int* __restrict__ bsum,
                             int* __restrict__ offs, int n, int e_total) {
    int i = blockIdx.x * blockDim.x + threadIdx.x;
    if (i < n) offs[i] = part[i] + bsum[i >> 10];
    if (i == 0) offs[n] = e_total;
}

__global__ void scatter_kernel(const int* __restrict__ src, const int* __restrict__ dst,
                               const float* __restrict__ ew, const float* __restrict__ dinv,
                               const int* __restrict__ offs, int* __restrict__ cursor,
                               int2* __restrict__ csr, int e_count) {
    int e = blockIdx.x * blockDim.x + threadIdx.x;
    if (e >= e_count) return;
    int sN = src[e], dN = dst[e];
    int pos = offs[dN] + atomicAdd(&cursor[dN], 1);
    float w = dinv[sN] * ew[e] * dinv[dN];
    csr[pos] = make_int2(sN, __float_as_int(w));
}

// ---------------- W -> bf16 hi/lo split in MFMA-fragment-major layout ----------------
// wtf[((kt*16 + nt)*64 + lane)*8 + j] = bf16(W[kt*32 + (lane>>4)*8 + j][nt*16 + (lane&15)])

__global__ __launch_bounds__(256) void wconvert_kernel(const float* __restrict__ W,
                                                       ushort_t* __restrict__ wtf_hi,
                                                       ushort_t* __restrict__ wtf_lo) {
    __shared__ ushort_t lds_hi[32][256];
    __shared__ ushort_t lds_lo[32][256];
    const int kt = blockIdx.x;
    const int tid = threadIdx.x;
    for (int c = 0; c < 32; ++c) {
        float f = W[(kt * 32 + c) * GCN_D + tid];
        unsigned u = __float_as_uint(f);
        ushort_t hi = (ushort_t)(u >> 16);               // truncation: exact residual
        float r = f - __uint_as_float(u & 0xFFFF0000u);
        lds_hi[c][tid] = hi;
        lds_lo[c][tid] = f2bf(r);
    }
    __syncthreads();
#pragma unroll
    for (int q = 0; q < 4; ++q) {
        int slot = q * 256 + tid;          // 0..1023 = nt*64 + lane
        int lane = slot & 63, nt = slot >> 6;
        int n = nt * 16 + (lane & 15);
        int kl = (lane >> 4) * 8;
        ushort_t h8[8], l8[8];
#pragma unroll
        for (int j = 0; j < 8; ++j) { h8[j] = lds_hi[kl + j][n]; l8[j] = lds_lo[kl + j][n]; }
        size_t o = ((size_t)(kt * 16 + nt) * 64 + lane) * 8;
#pragma unroll
        for (int j = 0; j < 8; ++j) { wtf_hi[o + j] = h8[j]; wtf_lo[o + j] = l8[j]; }
    }
}

// ---------------- MFMA GEMM (layer 1): fp32 x, split-precision ----------------
// 64-row blocks, 4 waves; each wave owns 16 rows x 256 cols (16 Ntiles).
// Per-wave private LDS epilogue tile -> no __syncthreads needed.

__device__ __forceinline__ void split_f32x8(float4 f0, float4 f1, bf16x8& hi, bf16x8& lo) {
    float f[8] = {f0.x, f0.y, f0.z, f0.w, f1.x, f1.y, f1.z, f1.w};
#pragma unroll
    for (int i = 0; i < 8; ++i) {
        unsigned u = __float_as_uint(f[i]);
        hi[i] = (short)(u >> 16);
        float r = f[i] - __uint_as_float(u & 0xFFFF0000u);
        lo[i] = (short)f2bf(r);
    }
}

__global__ __launch_bounds__(256) void mfma_gemm_f32_kernel(
        const float* __restrict__ x,          // [n_rows][256] fp32
        const ushort_t* __restrict__ wtf_hi,  // fragment-major bf16 bits
        const ushort_t* __restrict__ wtf_lo,
        const float* __restrict__ bias,
        ushort_t* __restrict__ out_h,         // [n_rows][256] bf16
        int n_rows) {
    __shared__ ushort_t csmem[4 * 16 * 264];
    const int lane = threadIdx.x & 63;
    const int wv   = threadIdx.x >> 6;
    const int r16  = lane & 15;
    const int kg   = lane >> 4;
    const int row0 = blockIdx.x * 64 + wv * 16;

    f32x4 acc[16];
#pragma unroll
    for (int nt = 0; nt < 16; ++nt) acc[nt] = (f32x4){0.f, 0.f, 0.f, 0.f};

#pragma unroll 2
    for (int kt = 0; kt < 8; ++kt) {
        bf16x8 a_hi, a_lo;
        {
            int row = row0 + r16;
            float4 f0 = make_float4(0.f, 0.f, 0.f, 0.f), f1 = f0;
            if (row < n_rows) {
                const float* p = &x[(size_t)row * GCN_D + kt * 32 + kg * 8];
                f0 = *(const float4*)p;
                f1 = *(const float4*)(p + 4);
            }
            split_f32x8(f0, f1, a_hi, a_lo);
        }
        const bf16x8* bhp = (const bf16x8*)wtf_hi + (size_t)kt * 16 * 64 + lane;
        const bf16x8* blp = (const bf16x8*)wtf_lo + (size_t)kt * 16 * 64 + lane;
#pragma unroll
        for (int nt = 0; nt < 16; ++nt) {
            bf16x8 bh = bhp[nt * 64];
            bf16x8 bl = blp[nt * 64];
            acc[nt] = __builtin_amdgcn_mfma_f32_16x16x32_bf16(a_hi, bh, acc[nt], 0, 0, 0);
            acc[nt] = __builtin_amdgcn_mfma_f32_16x16x32_bf16(a_lo, bh, acc[nt], 0, 0, 0);
            acc[nt] = __builtin_amdgcn_mfma_f32_16x16x32_bf16(a_hi, bl, acc[nt], 0, 0, 0);
        }
    }

    // C layout: col = lane&15, row = (lane>>4)*4 + reg. Wave-private LDS transpose.
    ushort_t* my = csmem + wv * (16 * 264);
#pragma unroll
    for (int nt = 0; nt < 16; ++nt) {
        float bv = bias[nt * 16 + r16];
#pragma unroll
        for (int r = 0; r < 4; ++r)
            my[(kg * 4 + r) * 264 + nt * 16 + r16] = f2bf(acc[nt][r] + bv);
    }
#pragma unroll 4
    for (int r = 0; r < 16; ++r) {
        int row = row0 + r;
        if (row < n_rows) {
            ushort4 v = *(ushort4*)&my[r * 264 + lane * 4];
            *(ushort4*)&out_h[(size_t)row * GCN_D + lane * 4] = v;
        }
    }
}

// ---------------- MFMA GEMM (layers 2,3): bf16 A, W_hi only ----------------

__global__ __launch_bounds__(256) void mfma_gemm_bf16_kernel(
        const ushort_t* __restrict__ a_in,    // [n_rows][256] bf16
        const ushort_t* __restrict__ wtf_hi,
        const float* __restrict__ bias,
        ushort_t* __restrict__ out_h,         // [n_rows][256] bf16
        int n_rows) {
    __shared__ ushort_t csmem[4 * 16 * 264];
    const int lane = threadIdx.x & 63;
    const int wv   = threadIdx.x >> 6;
    const int r16  = lane & 15;
    const int kg   = lane >> 4;
    const int row0 = blockIdx.x * 64 + wv * 16;

    f32x4 acc[16];
#pragma unroll
    for (int nt = 0; nt < 16; ++nt) acc[nt] = (f32x4){0.f, 0.f, 0.f, 0.f};

#pragma unroll 2
    for (int kt = 0; kt < 8; ++kt) {
        bf16x8 a = (bf16x8){0, 0, 0, 0, 0, 0, 0, 0};
        {
            int row = row0 + r16;
            if (row < n_rows)
                a = *(const bf16x8*)&a_in[(size_t)row * GCN_D + kt * 32 + kg * 8];
        }
        const bf16x8* bhp = (const bf16x8*)wtf_hi + (size_t)kt * 16 * 64 + lane;
#pragma unroll
        for (int nt = 0; nt < 16; ++nt) {
            bf16x8 bh = bhp[nt * 64];
            acc[nt] = __builtin_amdgcn_mfma_f32_16x16x32_bf16(a, bh, acc[nt], 0, 0, 0);
        }
    }

    ushort_t* my = csmem + wv * (16 * 264);
#pragma unroll
    for (int nt = 0; nt < 16; ++nt) {
        float bv = bias[nt * 16 + r16];
#pragma unroll
        for (int r = 0; r < 4; ++r)
            my[(kg * 4 + r) * 264 + nt * 16 + r16] = f2bf(acc[nt][r] + bv);
    }
#pragma unroll 4
    for (int r = 0; r < 16; ++r) {
        int row = row0 + r;
        if (row < n_rows) {
            ushort4 v = *(ushort4*)&my[r * 264 + lane * 4];
            *(ushort4*)&out_h[(size_t)row * GCN_D + lane * 4] = v;
        }
    }
}

// ---------------- SpMM: agg = A_norm*h + diag(1/deg)*h ----------------
// one wave per node; bf16 gathers (8B/lane), CSR packed int2, unroll x8.
// OUT_BF16: write bf16 + relu (layers 1,2). else fp32, no relu (layer 3).

template <int OUT_BF16>
__global__ __launch_bounds__(256) void spmm_kernel(const ushort_t* __restrict__ h,
                                                   const int* __restrict__ offs,
                                                   const int2* __restrict__ csr,
                                                   const float* __restrict__ invdeg,
                                                   void* __restrict__ outp, int n) {
    int wid = (blockIdx.x * blockDim.x + threadIdx.x) >> 6;
    int lane = threadIdx.x & 63;
    if (wid >= n) return;
    const ushort4* h4 = (const ushort4*)h;
    ushort4 sv = h4[(size_t)wid * 64 + lane];
    float sw = invdeg[wid];
    float4 acc;
    acc.x = bf2f(sv.x) * sw; acc.y = bf2f(sv.y) * sw;
    acc.z = bf2f(sv.z) * sw; acc.w = bf2f(sv.w) * sw;
    int e0 = offs[wid], e1 = offs[wid + 1];
    int k = e0;
    for (; k + 8 <= e1; k += 8) {
        int2 ee[8]; ushort4 vv[8];
#pragma unroll
        for (int u = 0; u < 8; ++u) ee[u] = csr[k + u];
#pragma unroll
        for (int u = 0; u < 8; ++u) vv[u] = h4[(size_t)ee[u].x * 64 + lane];
#pragma unroll
        for (int u = 0; u < 8; ++u) {
            float w = __int_as_float(ee[u].y);
            acc.x = fmaf(w, bf2f(vv[u].x), acc.x);
            acc.y = fmaf(w, bf2f(vv[u].y), acc.y);
            acc.z = fmaf(w, bf2f(vv[u].z), acc.z);
            acc.w = fmaf(w, bf2f(vv[u].w), acc.w);
        }
    }
    for (; k < e1; ++k) {
        int2 e = csr[k];
        float w = __int_as_float(e.y);
        ushort4 hv = h4[(size_t)e.x * 64 + lane];
        acc.x = fmaf(w, bf2f(hv.x), acc.x);
        acc.y = fmaf(w, bf2f(hv.y), acc.y);
        acc.z = fmaf(w, bf2f(hv.z), acc.z);
        acc.w = fmaf(w, bf2f(hv.w), acc.w);
    }
    if (OUT_BF16) {
        ushort4 o;
        o.x = f2bf(fmaxf(acc.x, 0.f));
        o.y = f2bf(fmaxf(acc.y, 0.f));
        o.z = f2bf(fmaxf(acc.z, 0.f));
        o.w = f2bf(fmaxf(acc.w, 0.f));
        ((ushort4*)outp)[(size_t)wid * 64 + lane] = o;
    } else {
        ((float4*)outp)[(size_t)wid * 64 + lane] = acc;
    }
}

// ---------------- launch ----------------

extern "C" void kernel_launch(void* const* d_in, const int* in_sizes, int n_in,
                              void* d_out, int out_size, void* d_ws, size_t ws_size,
                              hipStream_t stream) {
    const float* x    = (const float*)d_in[0];
    const int*   ei   = (const int*)d_in[1];
    const float* attr = (const float*)d_in[2];
    const float* W1 = (const float*)d_in[3];  const float* b1 = (const float*)d_in[4];
    const float* W2 = (const float*)d_in[5];  const float* b2 = (const float*)d_in[6];
    const float* W3 = (const float*)d_in[7];  const float* b3 = (const float*)d_in[8];
    const float* mw1 = (const float*)d_in[9]; const float* mb1 = (const float*)d_in[10];
    const float* mw2 = (const float*)d_in[11];const float* mb2 = (const float*)d_in[12];
    float* out = (float*)d_out;

    const int N = GCN_N, E = GCN_E;
    const int* srcI = ei;
    const int* dstI = ei + E;

    char* ws = (char*)d_ws;
    float* ew     = (float*)ws;                      ws += (size_t)E * 4;
    u64*   dc     = (u64*)(((uintptr_t)ws + 255) & ~(uintptr_t)255); ws = (char*)(dc + N);
    float* dinv   = (float*)ws;                      ws += (size_t)N * 4;
    float* invdeg = (float*)ws;                      ws += (size_t)N * 4;
    int*   cursor = (int*)ws;                        ws += (size_t)N * 4;
    int*   offs   = (int*)ws;                        ws += (size_t)(N + 1) * 4;
    int*   bsum   = (int*)ws;                        ws += 64 * 4;
    int*   part   = (int*)ws;                        ws += (size_t)N * 4;
    int2*  csr    = (int2*)(((uintptr_t)ws + 255) & ~(uintptr_t)255); ws = (char*)(csr + E);
    ushort_t* h   = (ushort_t*)(((uintptr_t)ws + 255) & ~(uintptr_t)255);  // N*256 bf16
    ws = (char*)(h + (size_t)N * GCN_D);
    ushort_t* act = (ushort_t*)(((uintptr_t)ws + 255) & ~(uintptr_t)255);  // N*256 bf16
    ws = (char*)(act + (size_t)N * GCN_D);
    ushort_t* wtf = (ushort_t*)(((uintptr_t)ws + 255) & ~(uintptr_t)255);
    ushort_t* wtf_hi1 = wtf;            // 65536 each
    ushort_t* wtf_lo1 = wtf + 65536;
    ushort_t* wtf_hi2 = wtf + 2 * 65536;
    ushort_t* wtf_lo2 = wtf + 3 * 65536;
    ushort_t* wtf_hi3 = wtf + 4 * 65536;
    ushort_t* wtf_lo3 = wtf + 5 * 65536;

    init_kernel<<<(N + 255) / 256, 256, 0, stream>>>(dc, cursor, N);
    edge_mlp_kernel<<<(E + 255) / 256, 256, 0, stream>>>(attr, dstI, mw1, mb1, mw2, mb2,
                                                         ew, dc, E);
    node_kernel<<<(N + 255) / 256, 256, 0, stream>>>(dc, dinv, invdeg, N);
    int nb = (N + 1023) / 1024;
    scan1_kernel<<<nb, 1024, 0, stream>>>(dc, part, bsum, N);
    scan2_kernel<<<1, 64, 0, stream>>>(bsum, nb);
    scan3_kernel<<<(N + 255) / 256, 256, 0, stream>>>(part, bsum, offs, N, E);
    scatter_kernel<<<(E + 255) / 256, 256, 0, stream>>>(srcI, dstI, ew, dinv, offs, cursor,
                                                        csr, E);
    wconvert_kernel<<<8, 256, 0, stream>>>(W1, wtf_hi1, wtf_lo1);
    wconvert_kernel<<<8, 256, 0, stream>>>(W2, wtf_hi2, wtf_lo2);
    wconvert_kernel<<<8, 256, 0, stream>>>(W3, wtf_hi3, wtf_lo3);

    const int gemm_grid = (N + 63) / 64;
    const int spmm_grid = (N * 64 + 255) / 256;

    // layer 1: x fp32 -> h ; spmm -> act (bf16, relu)
    mfma_gemm_f32_kernel<<<gemm_grid, 256, 0, stream>>>(x, wtf_hi1, wtf_lo1, b1, h, N);
    spmm_kernel<1><<<spmm_grid, 256, 0, stream>>>(h, offs, csr, invdeg, act, N);
    // layer 2: act bf16 -> h ; spmm -> act
    mfma_gemm_bf16_kernel<<<gemm_grid, 256, 0, stream>>>(act, wtf_hi2, b2, h, N);
    spmm_kernel<1><<<spmm_grid, 256, 0, stream>>>(h, offs, csr, invdeg, act, N);
    // layer 3: act bf16 -> h ; spmm -> d_out (fp32, no relu)
    mfma_gemm_bf16_kernel<<<gemm_grid, 256, 0, stream>>>(act, wtf_hi3, b3, h, N);
    spmm_kernel<0><<<spmm_grid, 256, 0, stream>>>(h, offs, csr, invdeg, out, N);
}

// Round 6
// 376.532 us; speedup vs baseline: 2.2670x; 1.0957x over previous
//
#include <hip/hip_runtime.h>
#include <hip/hip_bf16.h>
#include <stdint.h>

#define GCN_N 50000
#define GCN_E 800000
#define GCN_D 256

typedef __attribute__((ext_vector_type(8))) short bf16x8;
typedef __attribute__((ext_vector_type(4))) float f32x4;
typedef unsigned short ushort_t;
typedef unsigned long long u64;

__device__ __forceinline__ float bf2f(ushort_t u) {
    return __uint_as_float(((unsigned)u) << 16);
}
__device__ __forceinline__ ushort_t f2bf(float f) {
    unsigned v = __float_as_uint(f);
    v += 0x7FFFu + ((v >> 16) & 1u);   // round-to-nearest-even
    return (ushort_t)(v >> 16);
}

// ---------------- preprocessing kernels ----------------

__global__ void init_kernel(u64* dc, int n) {
    int i = blockIdx.x * blockDim.x + threadIdx.x;
    if (i < n) dc[i] = 0ull;
}

// dc[d] packs: count in bits [40..], sum(w) as 2^-32 fixed point in bits [0..40)
// atomic return value's count field = this edge's rank among its dst's edges.
__global__ void edge_mlp_kernel(const float* __restrict__ attr,
                                const int* __restrict__ dst,
                                const float* __restrict__ mw1, const float* __restrict__ mb1,
                                const float* __restrict__ mw2, const float* __restrict__ mb2,
                                float* __restrict__ ew, u64* __restrict__ dc,
                                int* __restrict__ rank, int e_count) {
    int e = blockIdx.x * blockDim.x + threadIdx.x;
    if (e >= e_count) return;
    float a = attr[e];
    float s = mb2[0];
#pragma unroll
    for (int j = 0; j < 8; ++j) {
        float hj = fmaf(a, mw1[j], mb1[j]);
        hj = fmaxf(hj, 0.0f);
        s = fmaf(hj, mw2[j], s);
    }
    float w = 1.0f / (1.0f + expf(-s));
    ew[e] = w;
    u64 pack = (1ull << 40) + (u64)((double)w * 4294967296.0);
    u64 old = atomicAdd(&dc[dst[e]], pack);
    rank[e] = (int)(old >> 40);
}

__global__ void node_kernel(const u64* __restrict__ dc, float* __restrict__ dinv,
                            float* __restrict__ invdeg, int n) {
    int i = blockIdx.x * blockDim.x + threadIdx.x;
    if (i < n) {
        u64 v = dc[i];
        float wsum = (float)((double)(v & ((1ull << 40) - 1)) * (1.0 / 4294967296.0));
        float d = 1.0f + wsum;
        dinv[i] = rsqrtf(d);
        invdeg[i] = 1.0f / d;
    }
}

__global__ __launch_bounds__(1024) void scan1_kernel(const u64* __restrict__ dc,
                                                     int* __restrict__ part,
                                                     int* __restrict__ bsum, int n) {
    __shared__ int s[1024];
    int tid = threadIdx.x;
    int i = blockIdx.x * 1024 + tid;
    int v = (i < n) ? (int)(dc[i] >> 40) : 0;
    s[tid] = v;
    __syncthreads();
#pragma unroll
    for (int d = 1; d < 1024; d <<= 1) {
        int t = (tid >= d) ? s[tid - d] : 0;
        __syncthreads();
        s[tid] += t;
        __syncthreads();
    }
    if (i < n) part[i] = s[tid] - v;  // exclusive within block
    if (tid == 1023) bsum[blockIdx.x] = s[1023];
}

// wave64 shuffle scan over block sums (nb <= 64)
__global__ void scan2_kernel(int* bsum, int nb) {
    int t = threadIdx.x;
    int orig = (t < nb) ? bsum[t] : 0;
    int v = orig;
#pragma unroll
    for (int d = 1; d < 64; d <<= 1) {
        int u = __shfl_up(v, d, 64);
        if (t >= d) v += u;
    }
    if (t < nb) bsum[t] = v - orig;   // exclusive
}

__global__ void scan3_kernel(const int* __restrict__ part, const int* __restrict__ bsum,
                             int* __restrict__ offs, int n, int e_total) {
    int i = blockIdx.x * blockDim.x + threadIdx.x;
    if (i < n) offs[i] = part[i] + bsum[i >> 10];
    if (i == 0) offs[n] = e_total;
}

// no atomics: position = offs[dst] + rank captured in edge_mlp
__global__ void scatter_kernel(const int* __restrict__ src, const int* __restrict__ dst,
                               const float* __restrict__ ew, const float* __restrict__ dinv,
                               const int* __restrict__ offs, const int* __restrict__ rank,
                               int2* __restrict__ csr, int e_count) {
    int e = blockIdx.x * blockDim.x + threadIdx.x;
    if (e >= e_count) return;
    int sN = src[e], dN = dst[e];
    int pos = offs[dN] + rank[e];
    float w = dinv[sN] * ew[e] * dinv[dN];
    csr[pos] = make_int2(sN, __float_as_int(w));
}

// ---------------- W -> bf16 hi/lo split in MFMA-fragment-major layout ----------------
// wtf[((kt*16 + nt)*64 + lane)*8 + j] = bf16(W[kt*32 + (lane>>4)*8 + j][nt*16 + (lane&15)])

__global__ __launch_bounds__(256) void wconvert_kernel(const float* __restrict__ W,
                                                       ushort_t* __restrict__ wtf_hi,
                                                       ushort_t* __restrict__ wtf_lo) {
    __shared__ ushort_t lds_hi[32][256];
    __shared__ ushort_t lds_lo[32][256];
    const int kt = blockIdx.x;
    const int tid = threadIdx.x;
    for (int c = 0; c < 32; ++c) {
        float f = W[(kt * 32 + c) * GCN_D + tid];
        unsigned u = __float_as_uint(f);
        ushort_t hi = (ushort_t)(u >> 16);               // truncation: exact residual
        float r = f - __uint_as_float(u & 0xFFFF0000u);
        lds_hi[c][tid] = hi;
        lds_lo[c][tid] = f2bf(r);
    }
    __syncthreads();
#pragma unroll
    for (int q = 0; q < 4; ++q) {
        int slot = q * 256 + tid;          // 0..1023 = nt*64 + lane
        int lane = slot & 63, nt = slot >> 6;
        int n = nt * 16 + (lane & 15);
        int kl = (lane >> 4) * 8;
        ushort_t h8[8], l8[8];
#pragma unroll
        for (int j = 0; j < 8; ++j) { h8[j] = lds_hi[kl + j][n]; l8[j] = lds_lo[kl + j][n]; }
        size_t o = ((size_t)(kt * 16 + nt) * 64 + lane) * 8;
#pragma unroll
        for (int j = 0; j < 8; ++j) { wtf_hi[o + j] = h8[j]; wtf_lo[o + j] = l8[j]; }
    }
}

// ---------------- MFMA GEMM (layer 1): fp32 x, split-precision ----------------
// Block = 32 rows x 256 cols, 4 waves: wave (wv>>1) picks row half, (wv&1) picks
// 8-Ntile column half. 6250 waves total (~6/SIMD), acc = 32 VGPR/wave.

__device__ __forceinline__ void split_f32x8(float4 f0, float4 f1, bf16x8& hi, bf16x8& lo) {
    float f[8] = {f0.x, f0.y, f0.z, f0.w, f1.x, f1.y, f1.z, f1.w};
#pragma unroll
    for (int i = 0; i < 8; ++i) {
        unsigned u = __float_as_uint(f[i]);
        hi[i] = (short)(u >> 16);
        float r = f[i] - __uint_as_float(u & 0xFFFF0000u);
        lo[i] = (short)f2bf(r);
    }
}

__global__ __launch_bounds__(256) void mfma_gemm_f32_kernel(
        const float* __restrict__ x,          // [n_rows][256] fp32
        const ushort_t* __restrict__ wtf_hi,  // fragment-major bf16 bits
        const ushort_t* __restrict__ wtf_lo,
        const float* __restrict__ bias,
        ushort_t* __restrict__ out_h,         // [n_rows][256] bf16
        int n_rows) {
    __shared__ ushort_t csmem[4 * 16 * 132];
    const int lane = threadIdx.x & 63;
    const int wv   = threadIdx.x >> 6;
    const int r16  = lane & 15;
    const int kg   = lane >> 4;
    const int row0 = blockIdx.x * 32 + (wv >> 1) * 16;
    const int nt0  = (wv & 1) * 8;

    f32x4 acc[8];
#pragma unroll
    for (int nt = 0; nt < 8; ++nt) acc[nt] = (f32x4){0.f, 0.f, 0.f, 0.f};

#pragma unroll 2
    for (int kt = 0; kt < 8; ++kt) {
        bf16x8 a_hi, a_lo;
        {
            int row = row0 + r16;
            float4 f0 = make_float4(0.f, 0.f, 0.f, 0.f), f1 = f0;
            if (row < n_rows) {
                const float* p = &x[(size_t)row * GCN_D + kt * 32 + kg * 8];
                f0 = *(const float4*)p;
                f1 = *(const float4*)(p + 4);
            }
            split_f32x8(f0, f1, a_hi, a_lo);
        }
        const bf16x8* bhp = (const bf16x8*)wtf_hi + ((size_t)kt * 16 + nt0) * 64 + lane;
        const bf16x8* blp = (const bf16x8*)wtf_lo + ((size_t)kt * 16 + nt0) * 64 + lane;
#pragma unroll
        for (int nt = 0; nt < 8; ++nt) {
            bf16x8 bh = bhp[nt * 64];
            bf16x8 bl = blp[nt * 64];
            acc[nt] = __builtin_amdgcn_mfma_f32_16x16x32_bf16(a_hi, bh, acc[nt], 0, 0, 0);
            acc[nt] = __builtin_amdgcn_mfma_f32_16x16x32_bf16(a_lo, bh, acc[nt], 0, 0, 0);
            acc[nt] = __builtin_amdgcn_mfma_f32_16x16x32_bf16(a_hi, bl, acc[nt], 0, 0, 0);
        }
    }

    // C layout: col = lane&15, row = (lane>>4)*4 + reg. Wave-private LDS tile,
    // stride 132 -> kg groups hit disjoint bank octets; no __syncthreads needed.
    ushort_t* my = csmem + wv * (16 * 132);
#pragma unroll
    for (int nt = 0; nt < 8; ++nt) {
        float bv = bias[(nt0 + nt) * 16 + r16];
#pragma unroll
        for (int r = 0; r < 4; ++r)
            my[(kg * 4 + r) * 132 + nt * 16 + r16] = f2bf(acc[nt][r] + bv);
    }
#pragma unroll 4
    for (int r = 0; r < 16; ++r) {
        int row = row0 + r;
        if (row < n_rows) {
            unsigned v = *(unsigned*)&my[r * 132 + lane * 2];
            *(unsigned*)&out_h[(size_t)row * GCN_D + nt0 * 16 + lane * 2] = v;
        }
    }
}

// ---------------- MFMA GEMM (layers 2,3): bf16 A, W_hi only ----------------

__global__ __launch_bounds__(256) void mfma_gemm_bf16_kernel(
        const ushort_t* __restrict__ a_in,    // [n_rows][256] bf16
        const ushort_t* __restrict__ wtf_hi,
        const float* __restrict__ bias,
        ushort_t* __restrict__ out_h,         // [n_rows][256] bf16
        int n_rows) {
    __shared__ ushort_t csmem[4 * 16 * 132];
    const int lane = threadIdx.x & 63;
    const int wv   = threadIdx.x >> 6;
    const int r16  = lane & 15;
    const int kg   = lane >> 4;
    const int row0 = blockIdx.x * 32 + (wv >> 1) * 16;
    const int nt0  = (wv & 1) * 8;

    f32x4 acc[8];
#pragma unroll
    for (int nt = 0; nt < 8; ++nt) acc[nt] = (f32x4){0.f, 0.f, 0.f, 0.f};

#pragma unroll 2
    for (int kt = 0; kt < 8; ++kt) {
        bf16x8 a = (bf16x8){0, 0, 0, 0, 0, 0, 0, 0};
        {
            int row = row0 + r16;
            if (row < n_rows)
                a = *(const bf16x8*)&a_in[(size_t)row * GCN_D + kt * 32 + kg * 8];
        }
        const bf16x8* bhp = (const bf16x8*)wtf_hi + ((size_t)kt * 16 + nt0) * 64 + lane;
#pragma unroll
        for (int nt = 0; nt < 8; ++nt) {
            bf16x8 bh = bhp[nt * 64];
            acc[nt] = __builtin_amdgcn_mfma_f32_16x16x32_bf16(a, bh, acc[nt], 0, 0, 0);
        }
    }

    ushort_t* my = csmem + wv * (16 * 132);
#pragma unroll
    for (int nt = 0; nt < 8; ++nt) {
        float bv = bias[(nt0 + nt) * 16 + r16];
#pragma unroll
        for (int r = 0; r < 4; ++r)
            my[(kg * 4 + r) * 132 + nt * 16 + r16] = f2bf(acc[nt][r] + bv);
    }
#pragma unroll 4
    for (int r = 0; r < 16; ++r) {
        int row = row0 + r;
        if (row < n_rows) {
            unsigned v = *(unsigned*)&my[r * 132 + lane * 2];
            *(unsigned*)&out_h[(size_t)row * GCN_D + nt0 * 16 + lane * 2] = v;
        }
    }
}

// ---------------- SpMM: agg = A_norm*h + diag(1/deg)*h ----------------
// one wave per node; bf16 gathers (8B/lane), CSR packed int2, unroll x8.
// OUT_BF16: write bf16 + relu (layers 1,2). else fp32, no relu (layer 3).

template <int OUT_BF16>
__global__ __launch_bounds__(256) void spmm_kernel(const ushort_t* __restrict__ h,
                                                   const int* __restrict__ offs,
                                                   const int2* __restrict__ csr,
                                                   const float* __restrict__ invdeg,
                                                   void* __restrict__ outp, int n) {
    int wid = (blockIdx.x * blockDim.x + threadIdx.x) >> 6;
    int lane = threadIdx.x & 63;
    if (wid >= n) return;
    const ushort4* h4 = (const ushort4*)h;
    ushort4 sv = h4[(size_t)wid * 64 + lane];
    float sw = invdeg[wid];
    float4 acc;
    acc.x = bf2f(sv.x) * sw; acc.y = bf2f(sv.y) * sw;
    acc.z = bf2f(sv.z) * sw; acc.w = bf2f(sv.w) * sw;
    int e0 = offs[wid], e1 = offs[wid + 1];
    int k = e0;
    for (; k + 8 <= e1; k += 8) {
        int2 ee[8]; ushort4 vv[8];
#pragma unroll
        for (int u = 0; u < 8; ++u) ee[u] = csr[k + u];
#pragma unroll
        for (int u = 0; u < 8; ++u) vv[u] = h4[(size_t)ee[u].x * 64 + lane];
#pragma unroll
        for (int u = 0; u < 8; ++u) {
            float w = __int_as_float(ee[u].y);
            acc.x = fmaf(w, bf2f(vv[u].x), acc.x);
            acc.y = fmaf(w, bf2f(vv[u].y), acc.y);
            acc.z = fmaf(w, bf2f(vv[u].z), acc.z);
            acc.w = fmaf(w, bf2f(vv[u].w), acc.w);
        }
    }
    for (; k < e1; ++k) {
        int2 e = csr[k];
        float w = __int_as_float(e.y);
        ushort4 hv = h4[(size_t)e.x * 64 + lane];
        acc.x = fmaf(w, bf2f(hv.x), acc.x);
        acc.y = fmaf(w, bf2f(hv.y), acc.y);
        acc.z = fmaf(w, bf2f(hv.z), acc.z);
        acc.w = fmaf(w, bf2f(hv.w), acc.w);
    }
    if (OUT_BF16) {
        ushort4 o;
        o.x = f2bf(fmaxf(acc.x, 0.f));
        o.y = f2bf(fmaxf(acc.y, 0.f));
        o.z = f2bf(fmaxf(acc.z, 0.f));
        o.w = f2bf(fmaxf(acc.w, 0.f));
        ((ushort4*)outp)[(size_t)wid * 64 + lane] = o;
    } else {
        ((float4*)outp)[(size_t)wid * 64 + lane] = acc;
    }
}

// ---------------- launch ----------------

extern "C" void kernel_launch(void* const* d_in, const int* in_sizes, int n_in,
                              void* d_out, int out_size, void* d_ws, size_t ws_size,
                              hipStream_t stream) {
    const float* x    = (const float*)d_in[0];
    const int*   ei   = (const int*)d_in[1];
    const float* attr = (const float*)d_in[2];
    const float* W1 = (const float*)d_in[3];  const float* b1 = (const float*)d_in[4];
    const float* W2 = (const float*)d_in[5];  const float* b2 = (const float*)d_in[6];
    const float* W3 = (const float*)d_in[7];  const float* b3 = (const float*)d_in[8];
    const float* mw1 = (const float*)d_in[9]; const float* mb1 = (const float*)d_in[10];
    const float* mw2 = (const float*)d_in[11];const float* mb2 = (const float*)d_in[12];
    float* out = (float*)d_out;

    const int N = GCN_N, E = GCN_E;
    const int* srcI = ei;
    const int* dstI = ei + E;

    char* ws = (char*)d_ws;
    float* ew     = (float*)ws;                      ws += (size_t)E * 4;
    int*   rank   = (int*)ws;                        ws += (size_t)E * 4;
    u64*   dc     = (u64*)(((uintptr_t)ws + 255) & ~(uintptr_t)255); ws = (char*)(dc + N);
    float* dinv   = (float*)ws;                      ws += (size_t)N * 4;
    float* invdeg = (float*)ws;                      ws += (size_t)N * 4;
    int*   offs   = (int*)ws;                        ws += (size_t)(N + 1) * 4;
    int*   bsum   = (int*)ws;                        ws += 64 * 4;
    int*   part   = (int*)ws;                        ws += (size_t)N * 4;
    int2*  csr    = (int2*)(((uintptr_t)ws + 255) & ~(uintptr_t)255); ws = (char*)(csr + E);
    ushort_t* h   = (ushort_t*)(((uintptr_t)ws + 255) & ~(uintptr_t)255);  // N*256 bf16
    ws = (char*)(h + (size_t)N * GCN_D);
    ushort_t* act = (ushort_t*)(((uintptr_t)ws + 255) & ~(uintptr_t)255);  // N*256 bf16
    ws = (char*)(act + (size_t)N * GCN_D);
    ushort_t* wtf = (ushort_t*)(((uintptr_t)ws + 255) & ~(uintptr_t)255);
    ushort_t* wtf_hi1 = wtf;            // 65536 each
    ushort_t* wtf_lo1 = wtf + 65536;
    ushort_t* wtf_hi2 = wtf + 2 * 65536;
    ushort_t* wtf_lo2 = wtf + 3 * 65536;
    ushort_t* wtf_hi3 = wtf + 4 * 65536;
    ushort_t* wtf_lo3 = wtf + 5 * 65536;

    init_kernel<<<(N + 255) / 256, 256, 0, stream>>>(dc, N);
    edge_mlp_kernel<<<(E + 255) / 256, 256, 0, stream>>>(attr, dstI, mw1, mb1, mw2, mb2,
                                                         ew, dc, rank, E);
    node_kernel<<<(N + 255) / 256, 256, 0, stream>>>(dc, dinv, invdeg, N);
    int nb = (N + 1023) / 1024;
    scan1_kernel<<<nb, 1024, 0, stream>>>(dc, part, bsum, N);
    scan2_kernel<<<1, 64, 0, stream>>>(bsum, nb);
    scan3_kernel<<<(N + 255) / 256, 256, 0, stream>>>(part, bsum, offs, N, E);
    scatter_kernel<<<(E + 255) / 256, 256, 0, stream>>>(srcI, dstI, ew, dinv, offs, rank,
                                                        csr, E);
    wconvert_kernel<<<8, 256, 0, stream>>>(W1, wtf_hi1, wtf_lo1);
    wconvert_kernel<<<8, 256, 0, stream>>>(W2, wtf_hi2, wtf_lo2);
    wconvert_kernel<<<8, 256, 0, stream>>>(W3, wtf_hi3, wtf_lo3);

    const int gemm_grid = (N + 31) / 32;
    const int spmm_grid = (N * 64 + 255) / 256;

    // layer 1: x fp32 -> h ; spmm -> act (bf16, relu)
    mfma_gemm_f32_kernel<<<gemm_grid, 256, 0, stream>>>(x, wtf_hi1, wtf_lo1, b1, h, N);
    spmm_kernel<1><<<spmm_grid, 256, 0, stream>>>(h, offs, csr, invdeg, act, N);
    // layer 2: act bf16 -> h ; spmm -> act
    mfma_gemm_bf16_kernel<<<gemm_grid, 256, 0, stream>>>(act, wtf_hi2, b2, h, N);
    spmm_kernel<1><<<spmm_grid, 256, 0, stream>>>(h, offs, csr, invdeg, act, N);
    // layer 3: act bf16 -> h ; spmm -> d_out (fp32, no relu)
    mfma_gemm_bf16_kernel<<<gemm_grid, 256, 0, stream>>>(act, wtf_hi3, b3, h, N);
    spmm_kernel<0><<<spmm_grid, 256, 0, stream>>>(h, offs, csr, invdeg, out, N);
}